// Round 5
// baseline (485.204 us; speedup 1.0000x reference)
//
#include <hip/hip_runtime.h>
#include <hip/hip_bf16.h>
#include <cstdint>
#include <cstddef>

typedef __fp16 f16_t;
typedef __attribute__((ext_vector_type(8))) __fp16 f16x8;
typedef __attribute__((ext_vector_type(4))) __fp16 f16x4;
typedef __attribute__((ext_vector_type(2))) __fp16 h2_t;
typedef __attribute__((ext_vector_type(4))) float floatx4;

// ---------------------------------------------------------------- helpers
__device__ __forceinline__ void async_copy_16B(const void* g, void* l) {
  __builtin_amdgcn_global_load_lds(
      (const __attribute__((address_space(1))) void*)g,
      (__attribute__((address_space(3))) void*)l, 16, 0, 0);
}

// ---------------------------------------------------------------- prep
// Fused: cast x/w_in/w_out to f16 (5242880 float4s) and build packed f16
// weight-pair table wp[p][c], p=0..127:
//   p<126 : (w[p], w[p+1]) ; p==126 : (w[126], 0) ; p==127 : (0, w[0])
__global__ __launch_bounds__(256) void prep(
    const float* __restrict__ x, const float* __restrict__ w_in,
    const float* __restrict__ w_out, const float* __restrict__ w_dw,
    f16_t* __restrict__ x_h, f16_t* __restrict__ wi_h,
    f16_t* __restrict__ wo_h, h2_t* __restrict__ wp) {
  const int tid = blockIdx.x * 256 + threadIdx.x;
  if (tid < 5242880) {
    const float* src;
    f16_t* dst;
    int off;
    if (tid < 2097152) {
      src = x; dst = x_h; off = tid;
    } else if (tid < 4194304) {
      src = w_in; dst = wi_h; off = tid - 2097152;
    } else {
      src = w_out; dst = wo_h; off = tid - 4194304;
    }
    const float4 v = *(const float4*)(src + (size_t)off * 4);
    f16x4 o;
    o.x = (f16_t)v.x; o.y = (f16_t)v.y; o.z = (f16_t)v.z; o.w = (f16_t)v.w;
    *(f16x4*)(dst + (size_t)off * 4) = o;
  } else {
    const int idx = tid - 5242880;
    if (idx < 128 * 4096) {
      const int p = idx >> 12;
      const int c = idx & 4095;
      float a, b;
      if (p < 126) {
        a = w_dw[c * 127 + p]; b = w_dw[c * 127 + p + 1];
      } else if (p == 126) {
        a = w_dw[c * 127 + 126]; b = 0.f;
      } else {
        a = 0.f; b = w_dw[c * 127 + 0];
      }
      h2_t w;
      w.x = (f16_t)a; w.y = (f16_t)b;
      wp[idx] = w;
    }
  }
}

// ---------------------------------------------------------------- GEMM1
// 256x256 tile, BK=32, 8 waves (2M x 4N), FOUR-deep LDS ring (4 x 32 KB),
// one counted vmcnt(12) gate + 2 barriers per K-tile.
//
// Fragment-major LDS: each 16x32 MFMA fragment (1 KB) is contiguous;
// ds_read_b128 addr = fragbase + lane*16 -> lane groups of 8 cover all
// 32 banks exactly once: conflict-free, no swizzle math.
//
// Fragment interior permutation (THE round-4 bug, now fixed): reader
// lane l expects (row = l&15, kgroup = l>>4). global_load_lds writes
// LDS linearly in lane order, so the GLOBAL source must use the same
// mapping: chunk q (one wave = one 64-chunk fragment):
//   frag = q>>6, r = q&15, g = (q>>4)&3
//   global row = base + frag*16 + r, col = k0 + g*8 ; LDS off = q*16.
//
// Ring schedule at iteration tt (buffer bf = tt&3):
//   stage(tt+3 -> (tt+3)&3)   [buffer last read at tt-1; reads consumed
//                              before tt-1's close barrier]
//   vmcnt(12): 3 tiles x 4 loads newer -> tile tt fully landed (~3 tiles
//              of landing slack vs ~1 tile DMA time)
//   barrier ; 12 ds_read + 32 MFMA/wave ; barrier
// Tails: rem=2 -> vmcnt(8), rem=1 -> vmcnt(4), rem=0 -> vmcnt(0).
__global__ __launch_bounds__(512, 2) void gemm256_d4(
    const f16_t* __restrict__ A, const f16_t* __restrict__ B,
    f16_t* __restrict__ C, int M, int N, int K) {
  extern __shared__ char smem[];
  const int t = threadIdx.x;
  const int lane = t & 63;
  const int wave = t >> 6;
  const int wm = wave >> 2;  // 0..1 : 128-row half
  const int wn = wave & 3;   // 0..3 : 64-col strip

  // quad-rect XCD swizzle (verified: FETCH 270->98 MB). Bijective, 1024.
  const int bid = blockIdx.x;
  const int xcd = bid & 7;
  const int l = bid >> 3;      // 0..127
  const int quad = l >> 5;     // 0..3
  const int qm = (l >> 3) & 3; // 0..3
  const int qn = l & 7;        // 0..7
  const int m0 = ((xcd >> 1) * 8 + (quad >> 1) * 4 + qm) * 256;
  const int n0 = ((xcd & 1) * 16 + (quad & 1) * 8 + qn) * 256;

  auto stageTile = [&](int bf_, int k0) {
    char* base = smem + bf_ * 32768;
#pragma unroll
    for (int u = 0; u < 2; ++u) {
      const int q = u * 512 + t;
      const int row = ((q >> 6) << 4) + (q & 15);   // frag*16 + (lane&15)
      const int g = (q >> 4) & 3;                   // lane>>4
      async_copy_16B(A + (size_t)(m0 + row) * K + k0 + g * 8, base + q * 16);
    }
#pragma unroll
    for (int u = 0; u < 2; ++u) {
      const int q = u * 512 + t;
      const int row = ((q >> 6) << 4) + (q & 15);
      const int g = (q >> 4) & 3;
      async_copy_16B(B + (size_t)(n0 + row) * K + k0 + g * 8,
                     base + 16384 + q * 16);
    }
  };
  auto ldA = [&](int bf_, int blk) -> f16x8 {
    return *(const f16x8*)(smem + bf_ * 32768 + blk * 1024 + lane * 16);
  };
  auto ldB = [&](int bf_, int blk) -> f16x8 {
    return *(const f16x8*)(smem + bf_ * 32768 + 16384 + blk * 1024 +
                           lane * 16);
  };

  floatx4 acc[8][4] = {};
  const int kT = K / 32;  // 32

  stageTile(0, 0);
  stageTile(1, 32);
  stageTile(2, 64);
  for (int tt = 0; tt < kT; ++tt) {
    const int bf_ = tt & 3;
    const int rem = kT - 1 - tt;
    if (rem >= 3) {
      stageTile((tt + 3) & 3, (tt + 3) * 32);
      asm volatile("s_waitcnt vmcnt(12)" ::: "memory");
    } else if (rem == 2) {
      asm volatile("s_waitcnt vmcnt(8)" ::: "memory");
    } else if (rem == 1) {
      asm volatile("s_waitcnt vmcnt(4)" ::: "memory");
    } else {
      asm volatile("s_waitcnt vmcnt(0)" ::: "memory");
    }
    __builtin_amdgcn_s_barrier();

    f16x8 bfr[4];
#pragma unroll
    for (int j = 0; j < 4; ++j) bfr[j] = ldB(bf_, wn * 4 + j);
    __builtin_amdgcn_s_setprio(1);
#pragma unroll
    for (int ii = 0; ii < 8; ++ii) {
      const f16x8 af = ldA(bf_, wm * 8 + ii);
#pragma unroll
      for (int j = 0; j < 4; ++j)
        acc[ii][j] = __builtin_amdgcn_mfma_f32_16x16x32_f16(
            af, bfr[j], acc[ii][j], 0, 0, 0);
    }
    __builtin_amdgcn_s_setprio(0);
    __builtin_amdgcn_s_barrier();  // all reads of bf_ done before it is
                                   // re-staged at iteration tt+1
  }

  // C/D layout: col = lane&15, row = (lane>>4)*4 + reg
  const int cr = (lane >> 4) * 4;
  const int cc = lane & 15;
#pragma unroll
  for (int i = 0; i < 8; ++i)
#pragma unroll
    for (int j = 0; j < 4; ++j)
#pragma unroll
      for (int r = 0; r < 4; ++r) {
        const int row = m0 + wm * 128 + i * 16 + cr + r;
        const int col = n0 + wn * 64 + j * 16 + cc;
        C[(size_t)row * N + col] = (f16_t)acc[i][j][r];
      }
}

// ---------------------------------------------------------------- GEMM2
// Out-projection: BM=256, BN=128, BK=64, 512 thr, THREE-deep LDS ring
// (3 x 48 KB = 144 KiB), fragment-major layout, one vmcnt(12) gate +
// 2 barriers per K-tile. Grid = exactly 256 blocks (32m x 8n), XCD-mapped.
// Per-wave output 128x32 (acc[8][2]), 32 MFMA/wave/tile, 64 K-tiles.
// Fragments: A = 32 frags (16 blocks x 2 kh) = 32 KB; B = 16 frags at
// +32768. frag = block*2+kh. Interior permutation fixed as in GEMM1:
//   r = q&15, g = (q>>4)&3 ; global row = (frag>>1)*16 + r,
//   col = k0 + (frag&1)*32 + g*8 ; LDS off = q*16.
__global__ __launch_bounds__(512, 2) void gemmN128_d3(
    const f16_t* __restrict__ A, const f16_t* __restrict__ B,
    float* __restrict__ C, int M, int N, int K) {
  extern __shared__ char smem[];
  const int t = threadIdx.x;
  const int lane = t & 63;
  const int wave = t >> 6;
  const int wm = wave >> 2;  // 0..1
  const int wn = wave & 3;   // 0..3

  const int bid = blockIdx.x;
  const int xcd = bid & 7;
  const int l = bid >> 3;                     // 0..31
  const int m0 = (xcd * 4 + (l >> 3)) * 256;  // 32 m-tiles
  const int n0 = (l & 7) * 128;               // 8 n-tiles

  auto stageTile = [&](int bf_, int k0) {
    char* base = smem + bf_ * 49152;
#pragma unroll
    for (int u = 0; u < 4; ++u) {  // A: 2048 chunks
      const int q = u * 512 + t;
      const int frag = q >> 6;
      const int row = (frag >> 1) * 16 + (q & 15);
      const int col = (frag & 1) * 32 + ((q >> 4) & 3) * 8;
      async_copy_16B(A + (size_t)(m0 + row) * K + k0 + col, base + q * 16);
    }
#pragma unroll
    for (int u = 0; u < 2; ++u) {  // B: 1024 chunks
      const int q = u * 512 + t;
      const int frag = q >> 6;
      const int row = (frag >> 1) * 16 + (q & 15);
      const int col = (frag & 1) * 32 + ((q >> 4) & 3) * 8;
      async_copy_16B(B + (size_t)(n0 + row) * K + k0 + col,
                     base + 32768 + q * 16);
    }
  };
  auto ldA = [&](int bf_, int frag) -> f16x8 {
    return *(const f16x8*)(smem + bf_ * 49152 + frag * 1024 + lane * 16);
  };
  auto ldB = [&](int bf_, int frag) -> f16x8 {
    return *(const f16x8*)(smem + bf_ * 49152 + 32768 + frag * 1024 +
                           lane * 16);
  };

  floatx4 acc[8][2] = {};
  const int kT = K / 64;  // 64

  stageTile(0, 0);
  stageTile(1, 64);
  for (int tt = 0; tt < kT; ++tt) {
    const int bf_ = tt % 3;
    const int rem = kT - 1 - tt;
    if (rem >= 2) {
      stageTile((tt + 2) % 3, (tt + 2) * 64);
      asm volatile("s_waitcnt vmcnt(12)" ::: "memory");
    } else if (rem == 1) {
      asm volatile("s_waitcnt vmcnt(6)" ::: "memory");
    } else {
      asm volatile("s_waitcnt vmcnt(0)" ::: "memory");
    }
    __builtin_amdgcn_s_barrier();

    f16x8 bfr[2][2];
#pragma unroll
    for (int j = 0; j < 2; ++j)
#pragma unroll
      for (int kh = 0; kh < 2; ++kh)
        bfr[j][kh] = ldB(bf_, (wn * 2 + j) * 2 + kh);
    __builtin_amdgcn_s_setprio(1);
#pragma unroll
    for (int ii = 0; ii < 8; ++ii) {
      const f16x8 af0 = ldA(bf_, (wm * 8 + ii) * 2 + 0);
      const f16x8 af1 = ldA(bf_, (wm * 8 + ii) * 2 + 1);
#pragma unroll
      for (int j = 0; j < 2; ++j)
        acc[ii][j] = __builtin_amdgcn_mfma_f32_16x16x32_f16(
            af0, bfr[j][0], acc[ii][j], 0, 0, 0);
#pragma unroll
      for (int j = 0; j < 2; ++j)
        acc[ii][j] = __builtin_amdgcn_mfma_f32_16x16x32_f16(
            af1, bfr[j][1], acc[ii][j], 0, 0, 0);
    }
    __builtin_amdgcn_s_setprio(0);
    __builtin_amdgcn_s_barrier();
  }

  const int cr = (lane >> 4) * 4;
  const int cc = lane & 15;
#pragma unroll
  for (int i = 0; i < 8; ++i)
#pragma unroll
    for (int j = 0; j < 2; ++j)
#pragma unroll
      for (int r = 0; r < 4; ++r) {
        const int row = m0 + wm * 128 + i * 16 + cr + r;
        const int col = n0 + wn * 32 + j * 16 + cc;
        C[(size_t)row * N + col] = acc[i][j][r];
      }
}

// ---------------------------------------------------------------- conv+gate
// vg: [8192][8192] f16 (v = cols 0..4095, g = cols 4096..8191)
// wp: [128][4096] packed f16 weight pairs ; y: [8192][4096] f16
// Block: 64 channels x 128 l-outputs; 4 waves x 32 l's, lane=channel.
#define CONV_L 128
#define CPAIRS 127  // (CONV_L + 126) / 2

__global__ __launch_bounds__(256) void conv_gate(
    const f16_t* __restrict__ vg, const h2_t* __restrict__ wp,
    const float* __restrict__ b_dw, f16_t* __restrict__ y) {
  __shared__ uint32_t vtp[CPAIRS * 64];  // 32.5 KB
  __shared__ uint32_t wpl[128 * 64];     // 32 KB
  const int t = threadIdx.x;
  const int lane = t & 63;
  const int wave = t >> 6;
  const int c0 = blockIdx.x * 64;
  const int lt = blockIdx.y & 31;   // 4096/128 l-tiles
  const int b = blockIdx.y >> 5;
  const int l0 = lt * CONV_L;

  // stage weight pairs wp[p][c0..c0+63] -> wpl via global->LDS DMA
#pragma unroll
  for (int it = 0; it < 8; ++it) {
    const int q = it * 256 + t;  // 2048 16B chunks: row = q>>4, 4 words each
    async_copy_16B(wp + (size_t)(q >> 4) * 4096 + c0 + (q & 15) * 4,
                   wpl + q * 4);
  }
  // stage v rows [l0-126, l0+127] pair-interleaved (zeros for l<0)
  for (int q = t; q < CPAIRS * 8; q += 256) {
    const int m = q >> 3;
    const int oc = (q & 7) * 8;
    const int le = l0 - 126 + 2 * m;  // always even
    uint4 a = make_uint4(0u, 0u, 0u, 0u);
    uint4 bb = make_uint4(0u, 0u, 0u, 0u);
    if (le >= 0) {
      const size_t base = (size_t)(b * 4096 + le) * 8192 + c0 + oc;
      a = *(const uint4*)(vg + base);
      bb = *(const uint4*)(vg + base + 8192);
    }
    uint32_t* dst = vtp + m * 64 + oc;
    const uint32_t aw[4] = {a.x, a.y, a.z, a.w};
    const uint32_t bw[4] = {bb.x, bb.y, bb.z, bb.w};
#pragma unroll
    for (int i = 0; i < 4; ++i) {
      dst[2 * i] = (aw[i] & 0xFFFFu) | (bw[i] << 16);
      dst[2 * i + 1] = (aw[i] >> 16) | (bw[i] & 0xFFFF0000u);
    }
  }

  const int c = c0 + lane;
  const int lb = l0 + wave * 32;
  // preload gate values (independent of LDS staging; latency hidden by FIR)
  const f16_t* gp = vg + (size_t)(b * 4096 + lb) * 8192 + 4096 + c;
  f16_t gvals[32];
#pragma unroll
  for (int i = 0; i < 32; ++i) gvals[i] = gp[(size_t)i * 8192];

  __syncthreads();

  const float bias = b_dw[c];
  float acc[32];
#pragma unroll
  for (int i = 0; i < 32; ++i) acc[i] = bias;

  // single-base immediate-offset LDS pointers
  const uint32_t* vbase = vtp + wave * 16 * 64 + lane;  // pair index of v[r0]
  const uint32_t* wbase = wpl + lane;

  // ring slot m holds pair (v[r0+2m], v[r0+2m+1]); slots 0..16
  h2_t ring[17];
#pragma unroll
  for (int m = 0; m < 17; ++m)
    ring[m] = __builtin_bit_cast(h2_t, vbase[m * 64]);

  // tap 0 for odd outputs: weight (0, w[0]) = wpl row 127
  {
    const h2_t w0 = __builtin_bit_cast(h2_t, wbase[127 * 64]);
#pragma unroll
    for (int h = 0; h < 16; ++h)
      acc[2 * h + 1] =
          __builtin_amdgcn_fdot2(w0, ring[h], acc[2 * h + 1], false);
  }

  // step k: even outs use row 2k (taps 2k,2k+1); odd outs row 2k+1
#pragma unroll
  for (int k = 0; k < 64; ++k) {
    const h2_t we = __builtin_bit_cast(h2_t, wbase[(2 * k) * 64]);
#pragma unroll
    for (int h = 0; h < 16; ++h)
      acc[2 * h] =
          __builtin_amdgcn_fdot2(we, ring[(k + h) % 17], acc[2 * h], false);
    if (k < 63) {
      const h2_t wo = __builtin_bit_cast(h2_t, wbase[(2 * k + 1) * 64]);
#pragma unroll
      for (int h = 0; h < 16; ++h)
        acc[2 * h + 1] = __builtin_amdgcn_fdot2(wo, ring[(k + 1 + h) % 17],
                                                acc[2 * h + 1], false);
      if (k < 62)  // slide: slot k%17 <- pair k+17
        ring[k % 17] = __builtin_bit_cast(h2_t, vbase[(17 + k) * 64]);
    }
  }

  f16_t* yp = y + (size_t)(b * 4096 + lb) * 4096 + c;
#pragma unroll
  for (int i = 0; i < 32; ++i) {
    const float gv = (float)gvals[i];
    const float v = acc[i];
    const float sv = v / (1.f + __expf(-v));
    const float sg = gv / (1.f + __expf(-gv));
    yp[(size_t)i * 4096] = (f16_t)(sv * sg);
  }
}

// ---------------------------------------------------------------- launch
extern "C" void kernel_launch(void* const* d_in, const int* in_sizes, int n_in,
                              void* d_out, int out_size, void* d_ws,
                              size_t ws_size, hipStream_t stream) {
  const float* x     = (const float*)d_in[0];  // [2,4096,1024]
  const float* w_in  = (const float*)d_in[1];  // [8192,1024]
  const float* w_dw  = (const float*)d_in[2];  // [4096,127]
  const float* b_dw  = (const float*)d_in[3];  // [4096]
  const float* w_out = (const float*)d_in[4];  // [1024,4096]
  float* out = (float*)d_out;                  // [2,4096,1024]

  char* p = (char*)d_ws;
  f16_t* x_h  = (f16_t*)p; p += (size_t)8192 * 1024 * 2;
  f16_t* wi_h = (f16_t*)p; p += (size_t)8192 * 1024 * 2;
  f16_t* wo_h = (f16_t*)p; p += (size_t)1024 * 4096 * 2;
  h2_t*  wp   = (h2_t*)p;  p += (size_t)128 * 4096 * 4;
  f16_t* vg   = (f16_t*)p; p += (size_t)8192 * 8192 * 2;
  f16_t* y    = (f16_t*)p; p += (size_t)8192 * 4096 * 2;

  // fused casts + packed weight-pair build
  prep<<<22528, 256, 0, stream>>>(x, w_in, w_out, w_dw, x_h, wi_h, wo_h, wp);

  // vg[8192,8192] = x[8192,1024] @ w_in[8192,1024]^T  (4-deep ring 256^2)
  hipFuncSetAttribute(reinterpret_cast<const void*>(gemm256_d4),
                      hipFuncAttributeMaxDynamicSharedMemorySize, 131072);
  gemm256_d4<<<1024, 512, 131072, stream>>>(x_h, wi_h, vg, 8192, 8192, 1024);

  // y = silu(causal_dwconv(v)+b) * silu(g)
  conv_gate<<<dim3(64, 64), 256, 0, stream>>>(vg, wp, b_dw, y);

  // out[8192,1024] = y[8192,4096] @ w_out[1024,4096]^T (3-deep ring 256x128)
  hipFuncSetAttribute(reinterpret_cast<const void*>(gemmN128_d3),
                      hipFuncAttributeMaxDynamicSharedMemorySize, 147456);
  gemmN128_d3<<<256, 512, 147456, stream>>>(y, wo_h, out, 8192, 1024, 4096);
}